// Round 1
// baseline (22.977 us; speedup 1.0000x reference)
//
#include <hip/hip_runtime.h>

// ---------------------------------------------------------------------------
// Precompute kernel: builds the four 81-element coefficient tensors C[mi][q]
// such that  z_q = sum_{mi} C[mi][q] * prod_q w_q[m_q],
// where w_q = (1+cos x_q, sin x_q, 1-cos x_q)   (1/16 folded into C).
//
// Derivation: psi = D r (r real tensor-product), final = V psi = U r with
// U = V*D.  z_q = sum over ordered pairs (j,k) of r_j r_k * M^q_jk,
// M^q_jk = sum_i sign_q(i) Re(conj(U_ij) U_ik).
// Pairs grouped by per-qubit signature m_q = j_q + k_q in {0,1,2}.
// ---------------------------------------------------------------------------
__global__ __launch_bounds__(256) void qprecomp(const float* __restrict__ params,
                                                float* __restrict__ C) {
  __shared__ float colR[16][16];   // colR[j][i] = Re U_ij
  __shared__ float colI[16][16];
  __shared__ float Um[12][8];      // per-gate 2x2 complex (m00,m01,m10,m11)
  __shared__ float4 S4[256];       // per ordered pair (j,k): the 4 signed sums
  const int t = threadIdx.x;

  // init columns of U = V*D: column j starts as (-i)^popcount(j) * e_j
  if (t < 16) {
#pragma unroll
    for (int i = 0; i < 16; ++i) { colR[t][i] = 0.0f; colI[t][i] = 0.0f; }
    int pc = __popc(t) & 3;
    colR[t][t] = (pc == 0) ? 1.0f : (pc == 2 ? -1.0f : 0.0f);
    colI[t][t] = (pc == 1) ? -1.0f : (pc == 3 ? 1.0f : 0.0f);
  }
  // Rot(phi,theta,omega) = RZ(om) RY(th) RZ(phi) matrices, one per (layer,qubit)
  if (t < 12) {
    float phi = params[t * 3 + 0], th = params[t * 3 + 1], om = params[t * 3 + 2];
    float sa, ca, sb, cb, s2, c2;
    __sincosf(0.5f * (phi + om), &sa, &ca);
    __sincosf(0.5f * (phi - om), &sb, &cb);
    __sincosf(0.5f * th, &s2, &c2);
    Um[t][0] =  c2 * ca; Um[t][1] = -c2 * sa;   // m00 = e^{-i a} c
    Um[t][2] = -s2 * cb; Um[t][3] = -s2 * sb;   // m01 = -e^{+i b} s
    Um[t][4] =  s2 * cb; Um[t][5] = -s2 * sb;   // m10 =  e^{-i b} s
    Um[t][6] =  c2 * ca; Um[t][7] =  c2 * sa;   // m11 = e^{+i a} c
  }
  __syncthreads();

  const int j = t >> 3, p = t & 7;  // column j, pair p (valid for t<128)
  for (int l = 0; l < 3; ++l) {
    // Rot on each qubit
    for (int q = 0; q < 4; ++q) {
      if (t < 128) {
        const int g = l * 4 + q;
        const int B = 3 - q, mask = 1 << B;                 // qubit q = bit (3-q)
        const int i0 = ((p >> B) << (B + 1)) | (p & (mask - 1));
        const int i1 = i0 | mask;
        float a0r = colR[j][i0], a0i = colI[j][i0];
        float a1r = colR[j][i1], a1i = colI[j][i1];
        float m00r = Um[g][0], m00i = Um[g][1], m01r = Um[g][2], m01i = Um[g][3];
        float m10r = Um[g][4], m10i = Um[g][5], m11r = Um[g][6], m11i = Um[g][7];
        colR[j][i0] = m00r * a0r - m00i * a0i + m01r * a1r - m01i * a1i;
        colI[j][i0] = m00r * a0i + m00i * a0r + m01r * a1i + m01i * a1r;
        colR[j][i1] = m10r * a0r - m10i * a0i + m11r * a1r - m11i * a1i;
        colI[j][i1] = m10r * a0i + m10i * a0r + m11r * a1i + m11i * a1r;
      }
      __syncthreads();
    }
    // CNOT chain q -> q+1: rows with control=1: swap target bit
    for (int q = 0; q < 3; ++q) {
      if (t < 64) {
        const int jj = t >> 2, pp = t & 3;
        const int Bc = 3 - q, Bt = 2 - q;
        int fps[2], nf = 0;
        for (int b = 0; b < 4; ++b)
          if (b != Bc && b != Bt) fps[nf++] = b;
        const int i  = (1 << Bc) | ((pp & 1) << fps[0]) | (((pp >> 1) & 1) << fps[1]);
        const int i2 = i | (1 << Bt);
        float tr = colR[jj][i], ti = colI[jj][i];
        colR[jj][i] = colR[jj][i2]; colI[jj][i] = colI[jj][i2];
        colR[jj][i2] = tr;          colI[jj][i2] = ti;
      }
      __syncthreads();
    }
  }

  // Gram stage: thread t = ordered pair (j,k); 4 signed sums over i
  {
    const int jj = t >> 4, k = t & 15;
    float s0 = 0.f, s1 = 0.f, s2 = 0.f, s3 = 0.f;
#pragma unroll
    for (int i = 0; i < 16; ++i) {
      float pr = colR[jj][i] * colR[k][i] + colI[jj][i] * colI[k][i];
      s0 += ((i >> 3) & 1) ? -pr : pr;   // qubit 0 = bit 3
      s1 += ((i >> 2) & 1) ? -pr : pr;
      s2 += ((i >> 1) & 1) ? -pr : pr;
      s3 += ( i       & 1) ? -pr : pr;
    }
    S4[t] = make_float4(s0, s1, s2, s3);
  }
  __syncthreads();

  // Fold ordered pairs into the 81 signature bins (deterministic fixed order)
  if (t < 81) {
    const int m[4] = { t / 27, (t / 9) % 3, (t / 3) % 3, t % 3 };
    float a0 = 0.f, a1 = 0.f, a2 = 0.f, a3 = 0.f;
    for (int c = 0; c < 16; ++c) {
      int jj = 0, kk = 0; bool ok = true;
      for (int q = 0; q < 4; ++q) {
        int jb, kb;
        if (m[q] == 1) { jb = (c >> q) & 1; kb = 1 - jb; }
        else { jb = kb = (m[q] >> 1); if ((c >> q) & 1) ok = false; }
        jj |= jb << (3 - q); kk |= kb << (3 - q);
      }
      if (!ok) continue;
      float4 sv = S4[jj * 16 + kk];
      a0 += sv.x; a1 += sv.y; a2 += sv.z; a3 += sv.w;
    }
    C[t * 4 + 0] = a0 * 0.0625f;   // fold 1/16 normalization of w
    C[t * 4 + 1] = a1 * 0.0625f;
    C[t * 4 + 2] = a2 * 0.0625f;
    C[t * 4 + 3] = a3 * 0.0625f;
  }
}

// ---------------------------------------------------------------------------
// Main kernel: 2 elements per thread; per element: 4 sincos, two 9-element
// tensor factors, 81-term x 4-output multilinear dot with uniform coeffs.
// ---------------------------------------------------------------------------
__device__ __forceinline__ void build_t(const float4 a, float* t01, float* t23) {
  float s0, c0, s1, c1, s2, c2, s3, c3;
  __sincosf(a.x, &s0, &c0);
  __sincosf(a.y, &s1, &c1);
  __sincosf(a.z, &s2, &c2);
  __sincosf(a.w, &s3, &c3);
  float w0[3] = { 1.0f + c0, s0, 1.0f - c0 };
  float w1[3] = { 1.0f + c1, s1, 1.0f - c1 };
  float w2[3] = { 1.0f + c2, s2, 1.0f - c2 };
  float w3[3] = { 1.0f + c3, s3, 1.0f - c3 };
#pragma unroll
  for (int i = 0; i < 3; ++i)
#pragma unroll
    for (int jj = 0; jj < 3; ++jj) {
      t01[i * 3 + jj] = w0[i] * w1[jj];
      t23[i * 3 + jj] = w2[i] * w3[jj];
    }
}

__global__ __launch_bounds__(256) void qmain(const float4* __restrict__ x4,
                                             const float4* __restrict__ C4,
                                             float4* __restrict__ out,
                                             int half) {
  const int gid = blockIdx.x * 256 + threadIdx.x;
  float tA01[9], tA23[9], tB01[9], tB23[9];
  build_t(x4[gid], tA01, tA23);
  build_t(x4[gid + half], tB01, tB23);

  float zA0 = 0.f, zA1 = 0.f, zA2 = 0.f, zA3 = 0.f;
  float zB0 = 0.f, zB1 = 0.f, zB2 = 0.f, zB3 = 0.f;
#pragma unroll
  for (int a = 0; a < 9; ++a) {
#pragma unroll
    for (int b = 0; b < 9; ++b) {
      const float4 c = C4[a * 9 + b];     // wave-uniform coefficient load
      const float pA = tA01[a] * tA23[b];
      const float pB = tB01[a] * tB23[b];
      zA0 = fmaf(c.x, pA, zA0); zA1 = fmaf(c.y, pA, zA1);
      zA2 = fmaf(c.z, pA, zA2); zA3 = fmaf(c.w, pA, zA3);
      zB0 = fmaf(c.x, pB, zB0); zB1 = fmaf(c.y, pB, zB1);
      zB2 = fmaf(c.z, pB, zB2); zB3 = fmaf(c.w, pB, zB3);
    }
  }
  out[gid]        = make_float4(zA0, zA1, zA2, zA3);
  out[gid + half] = make_float4(zB0, zB1, zB2, zB3);
}

extern "C" void kernel_launch(void* const* d_in, const int* in_sizes, int n_in,
                              void* d_out, int out_size, void* d_ws, size_t ws_size,
                              hipStream_t stream) {
  const float* x      = (const float*)d_in[0];
  const float* params = (const float*)d_in[1];
  float* C = (float*)d_ws;   // 324 floats

  qprecomp<<<1, 256, 0, stream>>>(params, C);

  const int M    = in_sizes[0] / 4;   // 1,048,576 patches
  const int half = M / 2;             // 524,288 threads, 2 elems each
  const int blocks = half / 256;      // 2048
  qmain<<<blocks, 256, 0, stream>>>((const float4*)x, (const float4*)C,
                                    (float4*)d_out, half);
}